// Round 2
// baseline (3228.845 us; speedup 1.0000x reference)
//
#include <hip/hip_runtime.h>

// ---------------------------------------------------------------------------
// FALLBACK SpMM: out[r,:] += val * X[c,:]   (COO, atomic scatter)
// ---------------------------------------------------------------------------
__global__ __launch_bounds__(256) void spmm_k(const int* __restrict__ rows,
                                              const int* __restrict__ cols,
                                              const float* __restrict__ vals,
                                              const float* __restrict__ X,
                                              float* __restrict__ out, int nnz) {
    int gid = blockIdx.x * 256 + threadIdx.x;
    int e = gid >> 6;
    if (e >= nnz) return;
    int d = gid & 63;
    int r = rows[e], c = cols[e];
    float v = vals[e];
    float x = X[(size_t)c * 64 + d];
    atomicAdd(&out[(size_t)r * 64 + d], v * x);
}

// ---------------------------------------------------------------------------
// E0 = base + a + b   (fallback path only)
// ---------------------------------------------------------------------------
__global__ __launch_bounds__(256) void add3_kernel(const float* __restrict__ base,
                                                   const float* __restrict__ a,
                                                   const float* __restrict__ b,
                                                   float* __restrict__ outb, size_t n) {
    size_t i = (size_t)blockIdx.x * 256 + threadIdx.x;
    if (i >= n) return;
    outb[i] = base[i] + a[i] + b[i];
}

// ---------------------------------------------------------------------------
// CSR build: histogram of row ids
// ---------------------------------------------------------------------------
__global__ __launch_bounds__(256) void hist_k(const int* __restrict__ rows,
                                              int* __restrict__ cnt, int nnz) {
    int i = blockIdx.x * 256 + threadIdx.x;
    if (i < nnz) atomicAdd(&cnt[rows[i]], 1);
}

// per-256-chunk sums
__global__ __launch_bounds__(256) void scan_part(const int* __restrict__ cnt,
                                                 int* __restrict__ bsum, int n) {
    __shared__ int sh[256];
    int tid = threadIdx.x;
    int i = blockIdx.x * 256 + tid;
    sh[tid] = (i < n) ? cnt[i] : 0;
    __syncthreads();
    for (int st = 128; st > 0; st >>= 1) {
        if (tid < st) sh[tid] += sh[tid + st];
        __syncthreads();
    }
    if (tid == 0) bsum[blockIdx.x] = sh[0];
}

// single-block exclusive scan of block sums (nb <= 1024)
__global__ __launch_bounds__(1024) void scan_top(int* __restrict__ b, int nb) {
    __shared__ int sh[1024];
    int tid = threadIdx.x;
    int orig = (tid < nb) ? b[tid] : 0;
    sh[tid] = orig;
    __syncthreads();
    for (int st = 1; st < 1024; st <<= 1) {
        int v = (tid >= st) ? sh[tid - st] : 0;
        __syncthreads();
        sh[tid] += v;
        __syncthreads();
    }
    if (tid < nb) b[tid] = sh[tid] - orig;
}

// in-block exclusive scan + block offset -> row_ptr and cursor (in-place ok)
__global__ __launch_bounds__(256) void scan_final(const int* __restrict__ cnt,
                                                  const int* __restrict__ bsum,
                                                  int* __restrict__ rp,
                                                  int* __restrict__ cur, int n, int nnz) {
    __shared__ int sh[256];
    int tid = threadIdx.x;
    int i = blockIdx.x * 256 + tid;
    int orig = (i < n) ? cnt[i] : 0;
    sh[tid] = orig;
    __syncthreads();
    for (int st = 1; st < 256; st <<= 1) {
        int v = (tid >= st) ? sh[tid - st] : 0;
        __syncthreads();
        sh[tid] += v;
        __syncthreads();
    }
    int ex = sh[tid] - orig + bsum[blockIdx.x];
    if (i < n) { rp[i] = ex; cur[i] = ex; }
    if (i == n - 1) rp[n] = nnz;
}

// scatter edges into CSR order; (col, bits(val)) packed as int2
__global__ __launch_bounds__(256) void scatter_k(const int* __restrict__ rows,
                                                 const int* __restrict__ cols,
                                                 const float* __restrict__ vals,
                                                 int* __restrict__ cur,
                                                 int2* __restrict__ edge, int nnz) {
    int i = blockIdx.x * 256 + threadIdx.x;
    if (i >= nnz) return;
    int p = atomicAdd(&cur[rows[i]], 1);
    edge[p] = make_int2(cols[i], __float_as_int(vals[i]));
}

// ---------------------------------------------------------------------------
// Gather SpMM: one wave per output row, lane = column d.
// out = gather(row) [+ a0] [+ a1]
// ---------------------------------------------------------------------------
__global__ __launch_bounds__(256) void spmm_csr(const int* __restrict__ rp,
                                                const int2* __restrict__ edge,
                                                const float* __restrict__ X,
                                                const float* __restrict__ a0,
                                                const float* __restrict__ a1,
                                                float* __restrict__ out, int nrows) {
    int gid = blockIdx.x * 256 + threadIdx.x;
    int r = gid >> 6;
    if (r >= nrows) return;
    int d = gid & 63;
    int s = rp[r], e = rp[r + 1];
    float acc = 0.f;
    int i = s;
    for (; i + 4 <= e; i += 4) {
        int2 e0 = edge[i], e1 = edge[i + 1], e2 = edge[i + 2], e3 = edge[i + 3];
        float x0 = X[(size_t)e0.x * 64 + d];
        float x1 = X[(size_t)e1.x * 64 + d];
        float x2 = X[(size_t)e2.x * 64 + d];
        float x3 = X[(size_t)e3.x * 64 + d];
        acc += __int_as_float(e0.y) * x0;
        acc += __int_as_float(e1.y) * x1;
        acc += __int_as_float(e2.y) * x2;
        acc += __int_as_float(e3.y) * x3;
    }
    for (; i < e; ++i) {
        int2 ee = edge[i];
        acc += __int_as_float(ee.y) * X[(size_t)ee.x * 64 + d];
    }
    size_t o = (size_t)r * 64 + d;
    if (a0) acc += a0[o];
    if (a1) acc += a1[o];
    out[o] = acc;
}

// ---------------------------------------------------------------------------
// Key = E @ K, stored in (H, N, DH) layout.
// ---------------------------------------------------------------------------
__global__ __launch_bounds__(256) void key_gemm(const float* __restrict__ E,
                                                const float* __restrict__ K,
                                                float* __restrict__ Kout, int N) {
    __shared__ float Ksh[4096];
    int tid = threadIdx.x;
    for (int i = tid; i < 4096; i += 256) Ksh[i] = K[i];
    __syncthreads();
    int j = tid & 63, slot = tid >> 6;
    int n = blockIdx.x * 4 + slot;
    if (n >= N) return;
    const float* Er = E + (size_t)n * 64;
    float acc = 0.f;
#pragma unroll
    for (int kk = 0; kk < 64; ++kk) acc += Er[kk] * Ksh[kk * 64 + j];
    int h = j >> 4, dh = j & 15;
    Kout[((size_t)h * N + n) * 16 + dh] = acc;
}

// ---------------------------------------------------------------------------
// A^T B reduction: M[k, h*16+d2] = sum_n cur[n,k] * Key[h,n,d2]
// lane = k, wave(slot) = h. 16 register accumulators per thread; no LDS.
// Grid-chunked over rows; 16 atomicAdds per thread at the end.
// ---------------------------------------------------------------------------
#define ATB_ROWS 128
__global__ __launch_bounds__(256) void atb_k(const float* __restrict__ cur,
                                             const float* __restrict__ Key,
                                             float* __restrict__ M, int N) {
    int tid = threadIdx.x;
    int k = tid & 63, h = tid >> 6;
    const float* Kh = Key + (size_t)h * N * 16;
    float acc[16];
#pragma unroll
    for (int i = 0; i < 16; ++i) acc[i] = 0.f;
    int s = blockIdx.x * ATB_ROWS;
    int e = s + ATB_ROWS;
    if (e > N) e = N;
#pragma unroll 2
    for (int n = s; n < e; ++n) {
        float c = cur[(size_t)n * 64 + k];
        const float4* kr = (const float4*)(Kh + (size_t)n * 16);
        float4 k0 = kr[0], k1 = kr[1], k2 = kr[2], k3 = kr[3];
        acc[0]  += c * k0.x;  acc[1]  += c * k0.y;  acc[2]  += c * k0.z;  acc[3]  += c * k0.w;
        acc[4]  += c * k1.x;  acc[5]  += c * k1.y;  acc[6]  += c * k1.z;  acc[7]  += c * k1.w;
        acc[8]  += c * k2.x;  acc[9]  += c * k2.y;  acc[10] += c * k2.z;  acc[11] += c * k2.w;
        acc[12] += c * k3.x;  acc[13] += c * k3.y;  acc[14] += c * k3.z;  acc[15] += c * k3.w;
    }
#pragma unroll
    for (int d2 = 0; d2 < 16; ++d2)
        atomicAdd(&M[k * 64 + h * 16 + d2], acc[d2]);
}

// ---------------------------------------------------------------------------
// VK[h,d1,d2] = sum_k pV[k, h*16+d1] * M[k, h*16+d2]     (1024 outputs)
// ---------------------------------------------------------------------------
__global__ __launch_bounds__(256) void vk_small(const float* __restrict__ M,
                                                const float* __restrict__ pV,
                                                float* __restrict__ VK) {
    int i = blockIdx.x * 256 + threadIdx.x;
    if (i >= 1024) return;
    int d2 = i & 15, d1 = (i >> 4) & 15, h = i >> 8;
    float s = 0.f;
#pragma unroll
    for (int k = 0; k < 64; ++k)
        s += pV[k * 64 + h * 16 + d1] * M[k * 64 + h * 16 + d2];
    VK[i] = s;
}

// ---------------------------------------------------------------------------
// t1[h*16+d1, m] = sum_d2 VK[h,d1,d2] * hyp[h,d2,m]      (64x128)
// ---------------------------------------------------------------------------
__global__ __launch_bounds__(256) void t1_kernel(const float* __restrict__ VK,
                                                 const float* __restrict__ hyp,
                                                 float* __restrict__ t1) {
    int i = blockIdx.x * 256 + threadIdx.x;
    if (i >= 8192) return;
    int m = i & 127, d = i >> 7;
    int h = d >> 4;
    float s = 0.f;
#pragma unroll
    for (int d2 = 0; d2 < 16; ++d2) s += VK[d * 16 + d2] * hyp[(h * 16 + d2) * 128 + m];
    t1[i] = s;
}

// ---------------------------------------------------------------------------
// tout = leaky(tin @ W^T) + tin   (64x128 @ 128x128^T)
// ---------------------------------------------------------------------------
__global__ __launch_bounds__(256) void ff_kernel(const float* __restrict__ tin,
                                                 const float* __restrict__ W,
                                                 float* __restrict__ tout) {
    int i = blockIdx.x * 256 + threadIdx.x;
    if (i >= 8192) return;
    int m = i & 127, d = i >> 7;
    const float* tr = tin + d * 128;
    const float* wr = W + m * 128;
    float s = 0.f;
#pragma unroll
    for (int mm = 0; mm < 128; ++mm) s += tr[mm] * wr[mm];
    float v = (s >= 0.f ? s : 0.5f * s) + tin[i];
    tout[i] = v;
}

// ---------------------------------------------------------------------------
// pre0[m, dd] = sum_d t3[d, m] * V[d, dd]   (128x64)
// ---------------------------------------------------------------------------
__global__ __launch_bounds__(256) void pre0_kernel(const float* __restrict__ t3,
                                                   const float* __restrict__ V,
                                                   float* __restrict__ pre0) {
    int i = blockIdx.x * 256 + threadIdx.x;
    if (i >= 8192) return;
    int dd = i & 63, m = i >> 6;
    float s = 0.f;
#pragma unroll
    for (int d = 0; d < 64; ++d) s += t3[d * 128 + m] * V[d * 64 + dd];
    pre0[m * 64 + dd] = s;
}

// ---------------------------------------------------------------------------
// pre2[h,d1,d2] = sum_m hyp[h,d1,m] * pre0[m, h*16+d2]   (4x16x16)
// ---------------------------------------------------------------------------
__global__ __launch_bounds__(256) void pre2_kernel(const float* __restrict__ hyp,
                                                   const float* __restrict__ pre0,
                                                   float* __restrict__ pre2) {
    int i = blockIdx.x * 256 + threadIdx.x;
    if (i >= 1024) return;
    int d2 = i & 15, d1 = (i >> 4) & 15, h = i >> 8;
    float s = 0.f;
#pragma unroll
    for (int m = 0; m < 128; ++m) s += hyp[(h * 16 + d1) * 128 + m] * pre0[m * 64 + h * 16 + d2];
    pre2[i] = s;
}

// ---------------------------------------------------------------------------
// Layer 0: new1 = Key@pre2 ; nxt = new1 ; tot = E0 + new1
// ---------------------------------------------------------------------------
__global__ __launch_bounds__(256) void expand0_kernel(const float* __restrict__ Key,
                                                      const float* __restrict__ pre2,
                                                      const float* __restrict__ E0,
                                                      float* __restrict__ nxt,
                                                      float* __restrict__ tot, int N) {
    __shared__ float p2[1024];
    int tid = threadIdx.x;
    for (int i = tid; i < 1024; i += 256) p2[i] = pre2[i];
    __syncthreads();
    int j = tid & 63, slot = tid >> 6;
    int n = blockIdx.x * 4 + slot;
    if (n >= N) return;
    int h = j >> 4, d2 = j & 15;
    const float* kr = Key + ((size_t)h * N + n) * 16;
    float s = 0.f;
#pragma unroll
    for (int d1 = 0; d1 < 16; ++d1) s += kr[d1] * p2[(h * 16 + d1) * 16 + d2];
    size_t o = (size_t)n * 64 + j;
    nxt[o] = s;
    tot[o] = E0[o] + s;
}

// ---------------------------------------------------------------------------
// Layer 1: outb = tot + Key@pre2
// ---------------------------------------------------------------------------
__global__ __launch_bounds__(256) void expand1_kernel(const float* __restrict__ Key,
                                                      const float* __restrict__ pre2,
                                                      const float* __restrict__ tot,
                                                      float* __restrict__ outb, int N) {
    __shared__ float p2[1024];
    int tid = threadIdx.x;
    for (int i = tid; i < 1024; i += 256) p2[i] = pre2[i];
    __syncthreads();
    int j = tid & 63, slot = tid >> 6;
    int n = blockIdx.x * 4 + slot;
    if (n >= N) return;
    int h = j >> 4, d2 = j & 15;
    const float* kr = Key + ((size_t)h * N + n) * 16;
    float s = 0.f;
#pragma unroll
    for (int d1 = 0; d1 < 16; ++d1) s += kr[d1] * p2[(h * 16 + d1) * 16 + d2];
    size_t o = (size_t)n * 64 + j;
    outb[o] = tot[o] + s;
}

// ---------------------------------------------------------------------------
// Build hyp3[k][h,dh,m] = Hyper[k][m, h*16+dh] and copy Hyper -> out
// ---------------------------------------------------------------------------
__global__ __launch_bounds__(256) void hyp_kernel(const float* __restrict__ Hyper,
                                                  float* __restrict__ hyp3,
                                                  float* __restrict__ out,
                                                  size_t off0, size_t off1, size_t off2) {
    int i = blockIdx.x * 256 + threadIdx.x;
    if (i >= 3 * 8192) return;
    int k = i / 8192, r = i % 8192;
    float v = Hyper[i];
    size_t off = (k == 0) ? off0 : ((k == 1) ? off1 : off2);
    out[off + r] = v;
    int m = r >> 6, dcol = r & 63;
    hyp3[k * 8192 + dcol * 128 + m] = v;
}

// ---------------------------------------------------------------------------
extern "C" void kernel_launch(void* const* d_in, const int* in_sizes, int n_in,
                              void* d_out, int out_size, void* d_ws, size_t ws_size,
                              hipStream_t stream) {
    const float* uE      = (const float*)d_in[0];
    const float* iE      = (const float*)d_in[1];
    const float* Ks      = (const float*)d_in[2];
    const float* Hyper   = (const float*)d_in[3];
    const float* Vt      = (const float*)d_in[4];
    const float* pV      = (const float*)d_in[5];
    const float* W1      = (const float*)d_in[6];
    const float* W2      = (const float*)d_in[7];
    const int* adj_rows  = (const int*)d_in[8];
    const int* adj_cols  = (const int*)d_in[9];
    const float* adj_vals= (const float*)d_in[10];
    const int* tp_rows   = (const int*)d_in[11];
    const int* tp_cols   = (const int*)d_in[12];
    const float* tp_vals = (const float*)d_in[13];
    const int* uu_rows   = (const int*)d_in[14];
    const int* uu_cols   = (const int*)d_in[15];
    const float* uu_vals = (const float*)d_in[16];

    const int U = in_sizes[0] / 64;
    const int I = in_sizes[1] / 64;
    const int nnz_ui = in_sizes[8];
    const int nnz_uu = in_sizes[14];
    const size_t UD = (size_t)U * 64, ID = (size_t)I * 64;

    // ws layout (floats): B1[UD] | B2[ID] | B3[UD] | CSR region.
    float* ws = (float*)d_ws;
    float* B1 = ws;           // h1u -> h1uu -> new1
    float* B2 = B1 + UD;      // h1i ; later: smalls
    float* B3 = B2 + ID;      // tot (and h2* in fallback)
    float* hyp3 = B2;                 // 3*8192 = 24576
    float* VKw  = hyp3 + 3 * 8192;    // 1024
    float* t1w  = VKw + 1024;         // 8192
    float* t2w  = t1w + 8192;         // 8192
    float* t3w  = t2w + 8192;         // 8192
    float* pre0w = t3w + 8192;        // 8192
    float* pre2w = pre0w + 8192;      // 1024
    float* Mw   = pre2w + 1024;       // 4096   (total smalls 63488 < ID)

    // CSR region (beyond the original 64 MB): 3 edge arrays + row_ptr/cursor.
    float* csrf   = B3 + UD;
    int2*  edge_a = (int2*)csrf;
    int2*  edge_t = edge_a + nnz_ui;
    int2*  edge_u = edge_t + nnz_ui;
    int*   rp_a   = (int*)(edge_u + nnz_uu);
    int*   cur_a  = rp_a + (U + 1);
    int*   rp_t   = cur_a + U;
    int*   cur_t  = rp_t + (I + 1);
    int*   rp_u   = cur_t + I;
    int*   cur_u  = rp_u + (U + 1);
    int*   bsum_a = cur_u + U;
    int*   bsum_t = bsum_a + 1024;
    int*   bsum_u = bsum_t + 1024;
    size_t need_bytes = (size_t)((char*)(bsum_u + 1024) - (char*)d_ws);
    const bool use_csr = (ws_size >= need_bytes) &&
                         ((U + 255) / 256 <= 1024) && ((I + 255) / 256 <= 1024);

    float* out = (float*)d_out;
    const size_t o_uE0 = 0;
    const size_t o_iE0 = UD;
    const size_t o_ulat = UD + ID;
    const size_t o_ilat = 2 * UD + ID;
    const size_t o_uKey = 2 * UD + 2 * ID;
    const size_t o_iKey = 3 * UD + 2 * ID;
    const size_t o_uHyp = 3 * UD + 3 * ID;
    const size_t o_iHyp = o_uHyp + 8192;
    const size_t o_uuE0 = o_iHyp + 8192;
    const size_t o_uulat = o_uuE0 + UD;
    const size_t o_uuKey = o_uulat + UD;
    const size_t o_uuHyp = o_uuKey + UD;

    const int gEU = (int)(((size_t)U * 64 + 255) / 256);
    const int gEI = (int)(((size_t)I * 64 + 255) / 256);

    if (use_csr) {
        // ---- build CSR for the three graphs ----
        auto build = [&](const int* rows, const int* cols, const float* vals,
                         int nnz, int n, int* rp, int* cur, int* bsum, int2* edge) {
            int nb = (n + 255) / 256;
            hipMemsetAsync(cur, 0, (size_t)n * sizeof(int), stream);
            hist_k<<<(nnz + 255) / 256, 256, 0, stream>>>(rows, cur, nnz);
            scan_part<<<nb, 256, 0, stream>>>(cur, bsum, n);
            scan_top<<<1, 1024, 0, stream>>>(bsum, nb);
            scan_final<<<nb, 256, 0, stream>>>(cur, bsum, rp, cur, n, nnz);
            scatter_k<<<(nnz + 255) / 256, 256, 0, stream>>>(rows, cols, vals, cur, edge, nnz);
        };
        build(adj_rows, adj_cols, adj_vals, nnz_ui, U, rp_a, cur_a, bsum_a, edge_a);
        build(tp_rows,  tp_cols,  tp_vals,  nnz_ui, I, rp_t, cur_t, bsum_t, edge_t);
        build(uu_rows,  uu_cols,  uu_vals,  nnz_uu, U, rp_u, cur_u, bsum_u, edge_u);

        // ---- hops as gather (no memsets, add3 fused) ----
        spmm_csr<<<gEI, 256, 0, stream>>>(rp_t, edge_t, uE, nullptr, nullptr, B2, I);
        spmm_csr<<<gEU, 256, 0, stream>>>(rp_a, edge_a, iE, nullptr, nullptr, B1, U);
        spmm_csr<<<gEU, 256, 0, stream>>>(rp_a, edge_a, B2, uE, B1, out + o_uE0, U);
        spmm_csr<<<gEI, 256, 0, stream>>>(rp_t, edge_t, B1, iE, B2, out + o_iE0, I);
        spmm_csr<<<gEU, 256, 0, stream>>>(rp_u, edge_u, uE, nullptr, nullptr, B1, U);
        spmm_csr<<<gEU, 256, 0, stream>>>(rp_u, edge_u, B1, uE, B1, out + o_uuE0, U);
    } else {
        // ---- fallback: original atomic-scatter path ----
        const int g_ui = (int)(((size_t)nnz_ui * 64 + 255) / 256);
        const int g_uu = (int)(((size_t)nnz_uu * 64 + 255) / 256);
        const int gU = (int)((UD + 255) / 256);
        const int gI = (int)((ID + 255) / 256);
        hipMemsetAsync(B1, 0, UD * sizeof(float), stream);
        spmm_k<<<g_ui, 256, 0, stream>>>(adj_rows, adj_cols, adj_vals, iE, B1, nnz_ui);
        hipMemsetAsync(B2, 0, ID * sizeof(float), stream);
        spmm_k<<<g_ui, 256, 0, stream>>>(tp_rows, tp_cols, tp_vals, uE, B2, nnz_ui);
        hipMemsetAsync(B3, 0, UD * sizeof(float), stream);
        spmm_k<<<g_ui, 256, 0, stream>>>(adj_rows, adj_cols, adj_vals, B2, B3, nnz_ui);
        add3_kernel<<<gU, 256, 0, stream>>>(uE, B1, B3, out + o_uE0, UD);
        hipMemsetAsync(B3, 0, ID * sizeof(float), stream);
        spmm_k<<<g_ui, 256, 0, stream>>>(tp_rows, tp_cols, tp_vals, B1, B3, nnz_ui);
        add3_kernel<<<gI, 256, 0, stream>>>(iE, B2, B3, out + o_iE0, ID);
        hipMemsetAsync(B1, 0, UD * sizeof(float), stream);
        spmm_k<<<g_uu, 256, 0, stream>>>(uu_rows, uu_cols, uu_vals, uE, B1, nnz_uu);
        hipMemsetAsync(B3, 0, UD * sizeof(float), stream);
        spmm_k<<<g_uu, 256, 0, stream>>>(uu_rows, uu_cols, uu_vals, B1, B3, nnz_uu);
        add3_kernel<<<gU, 256, 0, stream>>>(uE, B1, B3, out + o_uuE0, UD);
    }

    // hyp3 build + Hyper passthrough copies (first write into B2-alias region)
    hyp_kernel<<<(3 * 8192 + 255) / 256, 256, 0, stream>>>(Hyper, hyp3, out, o_uHyp, o_iHyp, o_uuHyp);

    const int    Narr[3] = { U, I, U };
    const size_t oE[3]   = { o_uE0, o_iE0, o_uuE0 };
    const size_t oK[3]   = { o_uKey, o_iKey, o_uuKey };
    const size_t oL[3]   = { o_ulat, o_ilat, o_uulat };

    for (int k = 0; k < 3; ++k) {
        int N = Narr[k];
        const float* E0k = out + oE[k];
        float* Keyk = out + oK[k];
        const float* Ksk = Ks + k * 4096;
        const float* pVk = pV + k * 4096;
        const float* Vk  = Vt + k * 4096;
        const float* hypk = hyp3 + k * 8192;

        key_gemm<<<(N + 3) / 4, 256, 0, stream>>>(E0k, Ksk, Keyk, N);

        for (int l = 0; l < 2; ++l) {
            const float* W1kl = W1 + (size_t)(k * 2 + l) * 16384;
            const float* W2kl = W2 + (size_t)(k * 2 + l) * 16384;

            hipMemsetAsync(Mw, 0, 4096 * sizeof(float), stream);
            atb_k<<<(N + ATB_ROWS - 1) / ATB_ROWS, 256, 0, stream>>>(
                (l == 0) ? E0k : B1, Keyk, Mw, N);
            vk_small<<<4, 256, 0, stream>>>(Mw, pVk, VKw);
            t1_kernel<<<32, 256, 0, stream>>>(VKw, hypk, t1w);
            ff_kernel<<<32, 256, 0, stream>>>(t1w, W1kl, t2w);
            ff_kernel<<<32, 256, 0, stream>>>(t2w, W2kl, t3w);
            pre0_kernel<<<32, 256, 0, stream>>>(t3w, Vk, pre0w);
            pre2_kernel<<<4, 256, 0, stream>>>(hypk, pre0w, pre2w);

            if (l == 0) {
                expand0_kernel<<<(N + 3) / 4, 256, 0, stream>>>(Keyk, pre2w, E0k, B1, B3, N);
            } else {
                expand1_kernel<<<(N + 3) / 4, 256, 0, stream>>>(Keyk, pre2w, B3, out + oL[k], N);
            }
        }
    }
}

// Round 3
// 1889.395 us; speedup vs baseline: 1.7089x; 1.7089x over previous
//
#include <hip/hip_runtime.h>

// ---------------------------------------------------------------------------
// FALLBACK SpMM: out[r,:] += val * X[c,:]   (COO, atomic scatter)
// ---------------------------------------------------------------------------
__global__ __launch_bounds__(256) void spmm_k(const int* __restrict__ rows,
                                              const int* __restrict__ cols,
                                              const float* __restrict__ vals,
                                              const float* __restrict__ X,
                                              float* __restrict__ out, int nnz) {
    int gid = blockIdx.x * 256 + threadIdx.x;
    int e = gid >> 6;
    if (e >= nnz) return;
    int d = gid & 63;
    int r = rows[e], c = cols[e];
    float v = vals[e];
    float x = X[(size_t)c * 64 + d];
    atomicAdd(&out[(size_t)r * 64 + d], v * x);
}

// ---------------------------------------------------------------------------
// E0 = base + a + b   (fallback path only)
// ---------------------------------------------------------------------------
__global__ __launch_bounds__(256) void add3_kernel(const float* __restrict__ base,
                                                   const float* __restrict__ a,
                                                   const float* __restrict__ b,
                                                   float* __restrict__ outb, size_t n) {
    size_t i = (size_t)blockIdx.x * 256 + threadIdx.x;
    if (i >= n) return;
    outb[i] = base[i] + a[i] + b[i];
}

// ---------------------------------------------------------------------------
// CSR build: histogram of row ids
// ---------------------------------------------------------------------------
__global__ __launch_bounds__(256) void hist_k(const int* __restrict__ rows,
                                              int* __restrict__ cnt, int nnz) {
    int i = blockIdx.x * 256 + threadIdx.x;
    if (i < nnz) atomicAdd(&cnt[rows[i]], 1);
}

// per-256-chunk sums
__global__ __launch_bounds__(256) void scan_part(const int* __restrict__ cnt,
                                                 int* __restrict__ bsum, int n) {
    __shared__ int sh[256];
    int tid = threadIdx.x;
    int i = blockIdx.x * 256 + tid;
    sh[tid] = (i < n) ? cnt[i] : 0;
    __syncthreads();
    for (int st = 128; st > 0; st >>= 1) {
        if (tid < st) sh[tid] += sh[tid + st];
        __syncthreads();
    }
    if (tid == 0) bsum[blockIdx.x] = sh[0];
}

// single-block exclusive scan of block sums (nb <= 1024)
__global__ __launch_bounds__(1024) void scan_top(int* __restrict__ b, int nb) {
    __shared__ int sh[1024];
    int tid = threadIdx.x;
    int orig = (tid < nb) ? b[tid] : 0;
    sh[tid] = orig;
    __syncthreads();
    for (int st = 1; st < 1024; st <<= 1) {
        int v = (tid >= st) ? sh[tid - st] : 0;
        __syncthreads();
        sh[tid] += v;
        __syncthreads();
    }
    if (tid < nb) b[tid] = sh[tid] - orig;
}

// in-block exclusive scan + block offset -> row_ptr and cursor (in-place ok)
__global__ __launch_bounds__(256) void scan_final(const int* __restrict__ cnt,
                                                  const int* __restrict__ bsum,
                                                  int* __restrict__ rp,
                                                  int* __restrict__ cur, int n, int nnz) {
    __shared__ int sh[256];
    int tid = threadIdx.x;
    int i = blockIdx.x * 256 + tid;
    int orig = (i < n) ? cnt[i] : 0;
    sh[tid] = orig;
    __syncthreads();
    for (int st = 1; st < 256; st <<= 1) {
        int v = (tid >= st) ? sh[tid - st] : 0;
        __syncthreads();
        sh[tid] += v;
        __syncthreads();
    }
    int ex = sh[tid] - orig + bsum[blockIdx.x];
    if (i < n) { rp[i] = ex; cur[i] = ex; }
    if (i == n - 1) rp[n] = nnz;
}

// scatter edges into CSR order; (col, bits(val)) packed as int2
__global__ __launch_bounds__(256) void scatter_k(const int* __restrict__ rows,
                                                 const int* __restrict__ cols,
                                                 const float* __restrict__ vals,
                                                 int* __restrict__ cur,
                                                 int2* __restrict__ edge, int nnz) {
    int i = blockIdx.x * 256 + threadIdx.x;
    if (i >= nnz) return;
    int p = atomicAdd(&cur[rows[i]], 1);
    edge[p] = make_int2(cols[i], __float_as_int(vals[i]));
}

// ---------------------------------------------------------------------------
// Gather SpMM: one wave per output row, lane = column d.
// out = gather(row) [+ a0] [+ a1]
// ---------------------------------------------------------------------------
__global__ __launch_bounds__(256) void spmm_csr(const int* __restrict__ rp,
                                                const int2* __restrict__ edge,
                                                const float* __restrict__ X,
                                                const float* __restrict__ a0,
                                                const float* __restrict__ a1,
                                                float* __restrict__ out, int nrows) {
    int gid = blockIdx.x * 256 + threadIdx.x;
    int r = gid >> 6;
    if (r >= nrows) return;
    int d = gid & 63;
    int s = rp[r], e = rp[r + 1];
    float acc = 0.f;
    int i = s;
    for (; i + 4 <= e; i += 4) {
        int2 e0 = edge[i], e1 = edge[i + 1], e2 = edge[i + 2], e3 = edge[i + 3];
        float x0 = X[(size_t)e0.x * 64 + d];
        float x1 = X[(size_t)e1.x * 64 + d];
        float x2 = X[(size_t)e2.x * 64 + d];
        float x3 = X[(size_t)e3.x * 64 + d];
        acc += __int_as_float(e0.y) * x0;
        acc += __int_as_float(e1.y) * x1;
        acc += __int_as_float(e2.y) * x2;
        acc += __int_as_float(e3.y) * x3;
    }
    for (; i < e; ++i) {
        int2 ee = edge[i];
        acc += __int_as_float(ee.y) * X[(size_t)ee.x * 64 + d];
    }
    size_t o = (size_t)r * 64 + d;
    if (a0) acc += a0[o];
    if (a1) acc += a1[o];
    out[o] = acc;
}

// ---------------------------------------------------------------------------
// Key = E @ K, stored in (H, N, DH) layout.
// ---------------------------------------------------------------------------
__global__ __launch_bounds__(256) void key_gemm(const float* __restrict__ E,
                                                const float* __restrict__ K,
                                                float* __restrict__ Kout, int N) {
    __shared__ float Ksh[4096];
    int tid = threadIdx.x;
    for (int i = tid; i < 4096; i += 256) Ksh[i] = K[i];
    __syncthreads();
    int j = tid & 63, slot = tid >> 6;
    int n = blockIdx.x * 4 + slot;
    if (n >= N) return;
    const float* Er = E + (size_t)n * 64;
    float acc = 0.f;
#pragma unroll
    for (int kk = 0; kk < 64; ++kk) acc += Er[kk] * Ksh[kk * 64 + j];
    int h = j >> 4, dh = j & 15;
    Kout[((size_t)h * N + n) * 16 + dh] = acc;
}

// ---------------------------------------------------------------------------
// A^T B partials: part[bid][k*64 + h*16+d2] = sum_{n in chunk} cur[n,k]*Key[h,n,d2]
// lane = k, wave(slot) = h. 16 register accumulators; NO atomics (round-2
// lesson: 3.2M atomics onto 4096 addrs serialized the L2 RMW pipe -> 370us).
// ---------------------------------------------------------------------------
#define ATB_BLOCKS 512
__global__ __launch_bounds__(256) void atb_part(const float* __restrict__ cur,
                                                const float* __restrict__ Key,
                                                float* __restrict__ part, int N, int chunk) {
    int tid = threadIdx.x;
    int k = tid & 63, h = tid >> 6;
    const float* Kh = Key + (size_t)h * N * 16;
    float acc[16];
#pragma unroll
    for (int i = 0; i < 16; ++i) acc[i] = 0.f;
    int s = blockIdx.x * chunk;
    int e = s + chunk;
    if (e > N) e = N;
#pragma unroll 2
    for (int n = s; n < e; ++n) {
        float c = cur[(size_t)n * 64 + k];
        const float4* kr = (const float4*)(Kh + (size_t)n * 16);
        float4 k0 = kr[0], k1 = kr[1], k2 = kr[2], k3 = kr[3];
        acc[0]  += c * k0.x;  acc[1]  += c * k0.y;  acc[2]  += c * k0.z;  acc[3]  += c * k0.w;
        acc[4]  += c * k1.x;  acc[5]  += c * k1.y;  acc[6]  += c * k1.z;  acc[7]  += c * k1.w;
        acc[8]  += c * k2.x;  acc[9]  += c * k2.y;  acc[10] += c * k2.z;  acc[11] += c * k2.w;
        acc[12] += c * k3.x;  acc[13] += c * k3.y;  acc[14] += c * k3.z;  acc[15] += c * k3.w;
    }
    float4* po = (float4*)(part + (size_t)blockIdx.x * 4096 + k * 64 + h * 16);
    po[0] = make_float4(acc[0],  acc[1],  acc[2],  acc[3]);
    po[1] = make_float4(acc[4],  acc[5],  acc[6],  acc[7]);
    po[2] = make_float4(acc[8],  acc[9],  acc[10], acc[11]);
    po[3] = make_float4(acc[12], acc[13], acc[14], acc[15]);
}

// M[i] = sum_b part[b][i]   (4096 outputs, nb partials)
__global__ __launch_bounds__(256) void reduce_m(const float* __restrict__ part,
                                                float* __restrict__ M, int nb) {
    int i = blockIdx.x * 256 + threadIdx.x;
    if (i >= 4096) return;
    float s = 0.f;
#pragma unroll 8
    for (int b = 0; b < nb; ++b) s += part[(size_t)b * 4096 + i];
    M[i] = s;
}

// ---------------------------------------------------------------------------
// FALLBACK A^T B with atomics (only if ws too small for partials)
// ---------------------------------------------------------------------------
#define ATB_ROWS 128
__global__ __launch_bounds__(256) void atb_k(const float* __restrict__ cur,
                                             const float* __restrict__ Key,
                                             float* __restrict__ M, int N) {
    int tid = threadIdx.x;
    int k = tid & 63, h = tid >> 6;
    const float* Kh = Key + (size_t)h * N * 16;
    float acc[16];
#pragma unroll
    for (int i = 0; i < 16; ++i) acc[i] = 0.f;
    int s = blockIdx.x * ATB_ROWS;
    int e = s + ATB_ROWS;
    if (e > N) e = N;
#pragma unroll 2
    for (int n = s; n < e; ++n) {
        float c = cur[(size_t)n * 64 + k];
        const float4* kr = (const float4*)(Kh + (size_t)n * 16);
        float4 k0 = kr[0], k1 = kr[1], k2 = kr[2], k3 = kr[3];
        acc[0]  += c * k0.x;  acc[1]  += c * k0.y;  acc[2]  += c * k0.z;  acc[3]  += c * k0.w;
        acc[4]  += c * k1.x;  acc[5]  += c * k1.y;  acc[6]  += c * k1.z;  acc[7]  += c * k1.w;
        acc[8]  += c * k2.x;  acc[9]  += c * k2.y;  acc[10] += c * k2.z;  acc[11] += c * k2.w;
        acc[12] += c * k3.x;  acc[13] += c * k3.y;  acc[14] += c * k3.z;  acc[15] += c * k3.w;
    }
#pragma unroll
    for (int d2 = 0; d2 < 16; ++d2)
        atomicAdd(&M[k * 64 + h * 16 + d2], acc[d2]);
}

// ---------------------------------------------------------------------------
// VK[h,d1,d2] = sum_k pV[k, h*16+d1] * M[k, h*16+d2]     (1024 outputs)
// ---------------------------------------------------------------------------
__global__ __launch_bounds__(256) void vk_small(const float* __restrict__ M,
                                                const float* __restrict__ pV,
                                                float* __restrict__ VK) {
    int i = blockIdx.x * 256 + threadIdx.x;
    if (i >= 1024) return;
    int d2 = i & 15, d1 = (i >> 4) & 15, h = i >> 8;
    float s = 0.f;
#pragma unroll
    for (int k = 0; k < 64; ++k)
        s += pV[k * 64 + h * 16 + d1] * M[k * 64 + h * 16 + d2];
    VK[i] = s;
}

// ---------------------------------------------------------------------------
// t1[h*16+d1, m] = sum_d2 VK[h,d1,d2] * hyp[h,d2,m]      (64x128)
// ---------------------------------------------------------------------------
__global__ __launch_bounds__(256) void t1_kernel(const float* __restrict__ VK,
                                                 const float* __restrict__ hyp,
                                                 float* __restrict__ t1) {
    int i = blockIdx.x * 256 + threadIdx.x;
    if (i >= 8192) return;
    int m = i & 127, d = i >> 7;
    int h = d >> 4;
    float s = 0.f;
#pragma unroll
    for (int d2 = 0; d2 < 16; ++d2) s += VK[d * 16 + d2] * hyp[(h * 16 + d2) * 128 + m];
    t1[i] = s;
}

// ---------------------------------------------------------------------------
// tout = leaky(tin @ W^T) + tin   (64x128 @ 128x128^T)
// ---------------------------------------------------------------------------
__global__ __launch_bounds__(256) void ff_kernel(const float* __restrict__ tin,
                                                 const float* __restrict__ W,
                                                 float* __restrict__ tout) {
    int i = blockIdx.x * 256 + threadIdx.x;
    if (i >= 8192) return;
    int m = i & 127, d = i >> 7;
    const float* tr = tin + d * 128;
    const float* wr = W + m * 128;
    float s = 0.f;
#pragma unroll
    for (int mm = 0; mm < 128; ++mm) s += tr[mm] * wr[mm];
    float v = (s >= 0.f ? s : 0.5f * s) + tin[i];
    tout[i] = v;
}

// ---------------------------------------------------------------------------
// pre0[m, dd] = sum_d t3[d, m] * V[d, dd]   (128x64)
// ---------------------------------------------------------------------------
__global__ __launch_bounds__(256) void pre0_kernel(const float* __restrict__ t3,
                                                   const float* __restrict__ V,
                                                   float* __restrict__ pre0) {
    int i = blockIdx.x * 256 + threadIdx.x;
    if (i >= 8192) return;
    int dd = i & 63, m = i >> 6;
    float s = 0.f;
#pragma unroll
    for (int d = 0; d < 64; ++d) s += t3[d * 128 + m] * V[d * 64 + dd];
    pre0[m * 64 + dd] = s;
}

// ---------------------------------------------------------------------------
// pre2[h,d1,d2] = sum_m hyp[h,d1,m] * pre0[m, h*16+d2]   (4x16x16)
// ---------------------------------------------------------------------------
__global__ __launch_bounds__(256) void pre2_kernel(const float* __restrict__ hyp,
                                                   const float* __restrict__ pre0,
                                                   float* __restrict__ pre2) {
    int i = blockIdx.x * 256 + threadIdx.x;
    if (i >= 1024) return;
    int d2 = i & 15, d1 = (i >> 4) & 15, h = i >> 8;
    float s = 0.f;
#pragma unroll
    for (int m = 0; m < 128; ++m) s += hyp[(h * 16 + d1) * 128 + m] * pre0[m * 64 + h * 16 + d2];
    pre2[i] = s;
}

// ---------------------------------------------------------------------------
// Layer 0: new1 = Key@pre2 ; nxt = new1 ; tot = E0 + new1
// ---------------------------------------------------------------------------
__global__ __launch_bounds__(256) void expand0_kernel(const float* __restrict__ Key,
                                                      const float* __restrict__ pre2,
                                                      const float* __restrict__ E0,
                                                      float* __restrict__ nxt,
                                                      float* __restrict__ tot, int N) {
    __shared__ float p2[1024];
    int tid = threadIdx.x;
    for (int i = tid; i < 1024; i += 256) p2[i] = pre2[i];
    __syncthreads();
    int j = tid & 63, slot = tid >> 6;
    int n = blockIdx.x * 4 + slot;
    if (n >= N) return;
    int h = j >> 4, d2 = j & 15;
    const float* kr = Key + ((size_t)h * N + n) * 16;
    float s = 0.f;
#pragma unroll
    for (int d1 = 0; d1 < 16; ++d1) s += kr[d1] * p2[(h * 16 + d1) * 16 + d2];
    size_t o = (size_t)n * 64 + j;
    nxt[o] = s;
    tot[o] = E0[o] + s;
}

// ---------------------------------------------------------------------------
// Layer 1: outb = tot + Key@pre2
// ---------------------------------------------------------------------------
__global__ __launch_bounds__(256) void expand1_kernel(const float* __restrict__ Key,
                                                      const float* __restrict__ pre2,
                                                      const float* __restrict__ tot,
                                                      float* __restrict__ outb, int N) {
    __shared__ float p2[1024];
    int tid = threadIdx.x;
    for (int i = tid; i < 1024; i += 256) p2[i] = pre2[i];
    __syncthreads();
    int j = tid & 63, slot = tid >> 6;
    int n = blockIdx.x * 4 + slot;
    if (n >= N) return;
    int h = j >> 4, d2 = j & 15;
    const float* kr = Key + ((size_t)h * N + n) * 16;
    float s = 0.f;
#pragma unroll
    for (int d1 = 0; d1 < 16; ++d1) s += kr[d1] * p2[(h * 16 + d1) * 16 + d2];
    size_t o = (size_t)n * 64 + j;
    outb[o] = tot[o] + s;
}

// ---------------------------------------------------------------------------
// Build hyp3[k][h,dh,m] = Hyper[k][m, h*16+dh] and copy Hyper -> out
// ---------------------------------------------------------------------------
__global__ __launch_bounds__(256) void hyp_kernel(const float* __restrict__ Hyper,
                                                  float* __restrict__ hyp3,
                                                  float* __restrict__ out,
                                                  size_t off0, size_t off1, size_t off2) {
    int i = blockIdx.x * 256 + threadIdx.x;
    if (i >= 3 * 8192) return;
    int k = i / 8192, r = i % 8192;
    float v = Hyper[i];
    size_t off = (k == 0) ? off0 : ((k == 1) ? off1 : off2);
    out[off + r] = v;
    int m = r >> 6, dcol = r & 63;
    hyp3[k * 8192 + dcol * 128 + m] = v;
}

// ---------------------------------------------------------------------------
extern "C" void kernel_launch(void* const* d_in, const int* in_sizes, int n_in,
                              void* d_out, int out_size, void* d_ws, size_t ws_size,
                              hipStream_t stream) {
    const float* uE      = (const float*)d_in[0];
    const float* iE      = (const float*)d_in[1];
    const float* Ks      = (const float*)d_in[2];
    const float* Hyper   = (const float*)d_in[3];
    const float* Vt      = (const float*)d_in[4];
    const float* pV      = (const float*)d_in[5];
    const float* W1      = (const float*)d_in[6];
    const float* W2      = (const float*)d_in[7];
    const int* adj_rows  = (const int*)d_in[8];
    const int* adj_cols  = (const int*)d_in[9];
    const float* adj_vals= (const float*)d_in[10];
    const int* tp_rows   = (const int*)d_in[11];
    const int* tp_cols   = (const int*)d_in[12];
    const float* tp_vals = (const float*)d_in[13];
    const int* uu_rows   = (const int*)d_in[14];
    const int* uu_cols   = (const int*)d_in[15];
    const float* uu_vals = (const float*)d_in[16];

    const int U = in_sizes[0] / 64;
    const int I = in_sizes[1] / 64;
    const int nnz_ui = in_sizes[8];
    const int nnz_uu = in_sizes[14];
    const size_t UD = (size_t)U * 64, ID = (size_t)I * 64;

    // ws layout (floats): B1[UD] | B2[ID] | B3[UD] | CSR region | partials.
    float* ws = (float*)d_ws;
    float* B1 = ws;           // h1u -> h1uu -> new1
    float* B2 = B1 + UD;      // h1i ; later: smalls
    float* B3 = B2 + ID;      // tot (and h2* in fallback)
    float* hyp3 = B2;                 // 3*8192 = 24576
    float* VKw  = hyp3 + 3 * 8192;    // 1024
    float* t1w  = VKw + 1024;         // 8192
    float* t2w  = t1w + 8192;         // 8192
    float* t3w  = t2w + 8192;         // 8192
    float* pre0w = t3w + 8192;        // 8192
    float* pre2w = pre0w + 8192;      // 1024
    float* Mw   = pre2w + 1024;       // 4096   (total smalls 63488 < ID)

    // CSR region (beyond the original 64 MB): 3 edge arrays + row_ptr/cursor.
    float* csrf   = B3 + UD;
    int2*  edge_a = (int2*)csrf;
    int2*  edge_t = edge_a + nnz_ui;
    int2*  edge_u = edge_t + nnz_ui;
    int*   rp_a   = (int*)(edge_u + nnz_uu);
    int*   cur_a  = rp_a + (U + 1);
    int*   rp_t   = cur_a + U;
    int*   cur_t  = rp_t + (I + 1);
    int*   rp_u   = cur_t + I;
    int*   cur_u  = rp_u + (U + 1);
    int*   bsum_a = cur_u + U;
    int*   bsum_t = bsum_a + 1024;
    int*   bsum_u = bsum_t + 1024;
    float* partw  = (float*)(bsum_u + 1024);   // ATB_BLOCKS * 4096 floats
    size_t need_bytes = (size_t)((char*)(partw + (size_t)ATB_BLOCKS * 4096) - (char*)d_ws);
    const bool use_csr = (ws_size >= need_bytes) &&
                         ((U + 255) / 256 <= 1024) && ((I + 255) / 256 <= 1024);

    float* out = (float*)d_out;
    const size_t o_uE0 = 0;
    const size_t o_iE0 = UD;
    const size_t o_ulat = UD + ID;
    const size_t o_ilat = 2 * UD + ID;
    const size_t o_uKey = 2 * UD + 2 * ID;
    const size_t o_iKey = 3 * UD + 2 * ID;
    const size_t o_uHyp = 3 * UD + 3 * ID;
    const size_t o_iHyp = o_uHyp + 8192;
    const size_t o_uuE0 = o_iHyp + 8192;
    const size_t o_uulat = o_uuE0 + UD;
    const size_t o_uuKey = o_uulat + UD;
    const size_t o_uuHyp = o_uuKey + UD;

    const int gEU = (int)(((size_t)U * 64 + 255) / 256);
    const int gEI = (int)(((size_t)I * 64 + 255) / 256);

    if (use_csr) {
        // ---- build CSR for the three graphs ----
        auto build = [&](const int* rows, const int* cols, const float* vals,
                         int nnz, int n, int* rp, int* cur, int* bsum, int2* edge) {
            int nb = (n + 255) / 256;
            hipMemsetAsync(cur, 0, (size_t)n * sizeof(int), stream);
            hist_k<<<(nnz + 255) / 256, 256, 0, stream>>>(rows, cur, nnz);
            scan_part<<<nb, 256, 0, stream>>>(cur, bsum, n);
            scan_top<<<1, 1024, 0, stream>>>(bsum, nb);
            scan_final<<<nb, 256, 0, stream>>>(cur, bsum, rp, cur, n, nnz);
            scatter_k<<<(nnz + 255) / 256, 256, 0, stream>>>(rows, cols, vals, cur, edge, nnz);
        };
        build(adj_rows, adj_cols, adj_vals, nnz_ui, U, rp_a, cur_a, bsum_a, edge_a);
        build(tp_rows,  tp_cols,  tp_vals,  nnz_ui, I, rp_t, cur_t, bsum_t, edge_t);
        build(uu_rows,  uu_cols,  uu_vals,  nnz_uu, U, rp_u, cur_u, bsum_u, edge_u);

        // ---- hops as gather (no memsets, add3 fused) ----
        spmm_csr<<<gEI, 256, 0, stream>>>(rp_t, edge_t, uE, nullptr, nullptr, B2, I);
        spmm_csr<<<gEU, 256, 0, stream>>>(rp_a, edge_a, iE, nullptr, nullptr, B1, U);
        spmm_csr<<<gEU, 256, 0, stream>>>(rp_a, edge_a, B2, uE, B1, out + o_uE0, U);
        spmm_csr<<<gEI, 256, 0, stream>>>(rp_t, edge_t, B1, iE, B2, out + o_iE0, I);
        spmm_csr<<<gEU, 256, 0, stream>>>(rp_u, edge_u, uE, nullptr, nullptr, B1, U);
        spmm_csr<<<gEU, 256, 0, stream>>>(rp_u, edge_u, B1, uE, B1, out + o_uuE0, U);
    } else {
        // ---- fallback: original atomic-scatter path ----
        const int g_ui = (int)(((size_t)nnz_ui * 64 + 255) / 256);
        const int g_uu = (int)(((size_t)nnz_uu * 64 + 255) / 256);
        const int gU = (int)((UD + 255) / 256);
        const int gI = (int)((ID + 255) / 256);
        hipMemsetAsync(B1, 0, UD * sizeof(float), stream);
        spmm_k<<<g_ui, 256, 0, stream>>>(adj_rows, adj_cols, adj_vals, iE, B1, nnz_ui);
        hipMemsetAsync(B2, 0, ID * sizeof(float), stream);
        spmm_k<<<g_ui, 256, 0, stream>>>(tp_rows, tp_cols, tp_vals, uE, B2, nnz_ui);
        hipMemsetAsync(B3, 0, UD * sizeof(float), stream);
        spmm_k<<<g_ui, 256, 0, stream>>>(adj_rows, adj_cols, adj_vals, B2, B3, nnz_ui);
        add3_kernel<<<gU, 256, 0, stream>>>(uE, B1, B3, out + o_uE0, UD);
        hipMemsetAsync(B3, 0, ID * sizeof(float), stream);
        spmm_k<<<g_ui, 256, 0, stream>>>(tp_rows, tp_cols, tp_vals, B1, B3, nnz_ui);
        add3_kernel<<<gI, 256, 0, stream>>>(iE, B2, B3, out + o_iE0, ID);
        hipMemsetAsync(B1, 0, UD * sizeof(float), stream);
        spmm_k<<<g_uu, 256, 0, stream>>>(uu_rows, uu_cols, uu_vals, uE, B1, nnz_uu);
        hipMemsetAsync(B3, 0, UD * sizeof(float), stream);
        spmm_k<<<g_uu, 256, 0, stream>>>(uu_rows, uu_cols, uu_vals, B1, B3, nnz_uu);
        add3_kernel<<<gU, 256, 0, stream>>>(uE, B1, B3, out + o_uuE0, UD);
    }

    // hyp3 build + Hyper passthrough copies (first write into B2-alias region)
    hyp_kernel<<<(3 * 8192 + 255) / 256, 256, 0, stream>>>(Hyper, hyp3, out, o_uHyp, o_iHyp, o_uuHyp);

    const int    Narr[3] = { U, I, U };
    const size_t oE[3]   = { o_uE0, o_iE0, o_uuE0 };
    const size_t oK[3]   = { o_uKey, o_iKey, o_uuKey };
    const size_t oL[3]   = { o_ulat, o_ilat, o_uulat };

    for (int k = 0; k < 3; ++k) {
        int N = Narr[k];
        const float* E0k = out + oE[k];
        float* Keyk = out + oK[k];
        const float* Ksk = Ks + k * 4096;
        const float* pVk = pV + k * 4096;
        const float* Vk  = Vt + k * 4096;
        const float* hypk = hyp3 + k * 8192;

        key_gemm<<<(N + 3) / 4, 256, 0, stream>>>(E0k, Ksk, Keyk, N);

        for (int l = 0; l < 2; ++l) {
            const float* W1kl = W1 + (size_t)(k * 2 + l) * 16384;
            const float* W2kl = W2 + (size_t)(k * 2 + l) * 16384;

            if (use_csr) {
                int chunk = (N + ATB_BLOCKS - 1) / ATB_BLOCKS;
                atb_part<<<ATB_BLOCKS, 256, 0, stream>>>(
                    (l == 0) ? E0k : B1, Keyk, partw, N, chunk);
                reduce_m<<<16, 256, 0, stream>>>(partw, Mw, ATB_BLOCKS);
            } else {
                hipMemsetAsync(Mw, 0, 4096 * sizeof(float), stream);
                atb_k<<<(N + ATB_ROWS - 1) / ATB_ROWS, 256, 0, stream>>>(
                    (l == 0) ? E0k : B1, Keyk, Mw, N);
            }
            vk_small<<<4, 256, 0, stream>>>(Mw, pVk, VKw);
            t1_kernel<<<32, 256, 0, stream>>>(VKw, hypk, t1w);
            ff_kernel<<<32, 256, 0, stream>>>(t1w, W1kl, t2w);
            ff_kernel<<<32, 256, 0, stream>>>(t2w, W2kl, t3w);
            pre0_kernel<<<32, 256, 0, stream>>>(t3w, Vk, pre0w);
            pre2_kernel<<<4, 256, 0, stream>>>(hypk, pre0w, pre2w);

            if (l == 0) {
                expand0_kernel<<<(N + 3) / 4, 256, 0, stream>>>(Keyk, pre2w, E0k, B1, B3, N);
            } else {
                expand1_kernel<<<(N + 3) / 4, 256, 0, stream>>>(Keyk, pre2w, B3, out + oL[k], N);
            }
        }
    }
}